// Round 3
// baseline (70.372 us; speedup 1.0000x reference)
//
#include <hip/hip_runtime.h>

#define NEG_FILL -10000000000.0f

typedef float f32x4 __attribute__((ext_vector_type(4)));

__device__ __forceinline__ f32x4 max4(f32x4 a, f32x4 b) {
    f32x4 r;
    r.x = fmaxf(a.x, b.x);
    r.y = fmaxf(a.y, b.y);
    r.z = fmaxf(a.z, b.z);
    r.w = fmaxf(a.w, b.w);
    return r;
}

// spans: [B=2048][L=13][S=4][D=1024] f32
// mask : [B=2048][S=4] i32
// out  : [B=2048][L=13][D=1024] f32 = max over S of (mask ? spans : NEG_FILL)
//
// Persistent per-batch blocks: 2048 blocks x 256 threads. Each block owns one
// b, loads the 4-int mask once (scalar), then loops over the 13 layers.
// #pragma unroll 4 keeps ~16 independent nontemporal loads in flight across
// iterations; per-block setup (dispatch, mask, base addresses) is paid once
// per 13 layers instead of once per layer.
__global__ __launch_bounds__(256) void MaxSpanRepr_kernel(
    const f32x4* __restrict__ spans,
    const int4* __restrict__ mask,
    f32x4* __restrict__ out) {
    const int D4 = 1024 / 4;  // 256 float4 per D-row
    int b = blockIdx.x;       // 0..2047
    int t = threadIdx.x;      // 0..255, one float4 of D each

    int4 mv = mask[b];  // uniform -> scalar load

    const f32x4* sb = spans + (size_t)b * 13 * 4 * D4 + t;
    f32x4* ob = out + (size_t)b * 13 * D4 + t;

    const f32x4 nf = {NEG_FILL, NEG_FILL, NEG_FILL, NEG_FILL};

#pragma unroll 4
    for (int l = 0; l < 13; ++l) {
        const f32x4* base = sb + l * 4 * D4;
        f32x4 a0 = nf, a1 = nf, a2 = nf, a3 = nf;
        if (mv.x != 0) a0 = __builtin_nontemporal_load(base + 0 * D4);
        if (mv.y != 0) a1 = __builtin_nontemporal_load(base + 1 * D4);
        if (mv.z != 0) a2 = __builtin_nontemporal_load(base + 2 * D4);
        if (mv.w != 0) a3 = __builtin_nontemporal_load(base + 3 * D4);
        f32x4 r = max4(max4(a0, a1), max4(a2, a3));
        __builtin_nontemporal_store(r, ob + l * D4);
    }
}

extern "C" void kernel_launch(void* const* d_in, const int* in_sizes, int n_in,
                              void* d_out, int out_size, void* d_ws, size_t ws_size,
                              hipStream_t stream) {
    const f32x4* spans = (const f32x4*)d_in[0];
    const int4* mask = (const int4*)d_in[1];
    f32x4* out = (f32x4*)d_out;

    const int B = 2048;
    dim3 grid(B);
    dim3 block(256);
    MaxSpanRepr_kernel<<<grid, block, 0, stream>>>(spans, mask, out);
}

// Round 4
// 59.597 us; speedup vs baseline: 1.1808x; 1.1808x over previous
//
#include <hip/hip_runtime.h>

#define NEG_FILL -10000000000.0f

typedef float f32x4 __attribute__((ext_vector_type(4)));

__device__ __forceinline__ f32x4 max4(f32x4 a, f32x4 b) {
    f32x4 r;
    r.x = fmaxf(a.x, b.x);
    r.y = fmaxf(a.y, b.y);
    r.z = fmaxf(a.z, b.z);
    r.w = fmaxf(a.w, b.w);
    return r;
}

// spans: [B=2048][L=13][S=4][D=1024] f32
// mask : [B=2048][S=4] i32
// out  : [B=2048][L=13][D=1024] f32 = max over S of (mask ? spans : NEG_FILL)
//
// One single-wave block (64 threads) per (b,l); each thread owns FOUR float4s
// of D (t, t+64, t+128, t+192). All conditional loads are value-only and
// hoisted: up to 16 nontemporal loads in flight per thread before the single
// wait at the reduction. Fine block granularity (26624 one-wave blocks)
// load-balances the random mask skips dynamically across CUs (R3 lesson:
// static per-batch assignment tails badly).
__global__ __launch_bounds__(64) void MaxSpanRepr_kernel(
    const f32x4* __restrict__ spans,
    const int4* __restrict__ mask,
    f32x4* __restrict__ out) {
    const int D4 = 1024 / 4;  // 256 float4 per D-row
    int bl = blockIdx.x;      // b*13 + l
    int b  = bl / 13;
    int t  = threadIdx.x;     // 0..63

    int4 mv = mask[b];  // uniform -> scalar load

    const f32x4* base = spans + (size_t)bl * 4 * D4 + t;

    const f32x4 nf = {NEG_FILL, NEG_FILL, NEG_FILL, NEG_FILL};
    f32x4 a0 = nf, a1 = nf, a2 = nf, a3 = nf;   // span 0, chunks 0..3
    f32x4 b0 = nf, b1 = nf, b2 = nf, b3 = nf;   // span 1
    f32x4 c0 = nf, c1 = nf, c2 = nf, c3 = nf;   // span 2
    f32x4 e0 = nf, e1 = nf, e2 = nf, e3 = nf;   // span 3

    if (mv.x != 0) {
        a0 = __builtin_nontemporal_load(base + 0 * D4 + 0);
        a1 = __builtin_nontemporal_load(base + 0 * D4 + 64);
        a2 = __builtin_nontemporal_load(base + 0 * D4 + 128);
        a3 = __builtin_nontemporal_load(base + 0 * D4 + 192);
    }
    if (mv.y != 0) {
        b0 = __builtin_nontemporal_load(base + 1 * D4 + 0);
        b1 = __builtin_nontemporal_load(base + 1 * D4 + 64);
        b2 = __builtin_nontemporal_load(base + 1 * D4 + 128);
        b3 = __builtin_nontemporal_load(base + 1 * D4 + 192);
    }
    if (mv.z != 0) {
        c0 = __builtin_nontemporal_load(base + 2 * D4 + 0);
        c1 = __builtin_nontemporal_load(base + 2 * D4 + 64);
        c2 = __builtin_nontemporal_load(base + 2 * D4 + 128);
        c3 = __builtin_nontemporal_load(base + 2 * D4 + 192);
    }
    if (mv.w != 0) {
        e0 = __builtin_nontemporal_load(base + 3 * D4 + 0);
        e1 = __builtin_nontemporal_load(base + 3 * D4 + 64);
        e2 = __builtin_nontemporal_load(base + 3 * D4 + 128);
        e3 = __builtin_nontemporal_load(base + 3 * D4 + 192);
    }

    f32x4 r0 = max4(max4(a0, b0), max4(c0, e0));
    f32x4 r1 = max4(max4(a1, b1), max4(c1, e1));
    f32x4 r2 = max4(max4(a2, b2), max4(c2, e2));
    f32x4 r3 = max4(max4(a3, b3), max4(c3, e3));

    f32x4* o = out + (size_t)bl * D4 + t;
    __builtin_nontemporal_store(r0, o + 0);
    __builtin_nontemporal_store(r1, o + 64);
    __builtin_nontemporal_store(r2, o + 128);
    __builtin_nontemporal_store(r3, o + 192);
}

extern "C" void kernel_launch(void* const* d_in, const int* in_sizes, int n_in,
                              void* d_out, int out_size, void* d_ws, size_t ws_size,
                              hipStream_t stream) {
    const f32x4* spans = (const f32x4*)d_in[0];
    const int4* mask = (const int4*)d_in[1];
    f32x4* out = (f32x4*)d_out;

    const int B = 2048, L = 13;
    dim3 grid(B * L);   // 26624 single-wave blocks
    dim3 block(64);
    MaxSpanRepr_kernel<<<grid, block, 0, stream>>>(spans, mask, out);
}